// Round 9
// baseline (433.108 us; speedup 1.0000x reference)
//
#include <hip/hip_runtime.h>
#include <hip/hip_bf16.h>

#define B_ 2048
#define T_ 64
#define H_ 256
#define V_ 51
#define Z_ 32
#define K_ 1000
#define LOG2E 1.4426950408889634f

typedef __bf16 bf16x8 __attribute__((ext_vector_type(8)));
typedef float floatx4 __attribute__((ext_vector_type(4)));

__device__ inline unsigned short f2bf(float f){
    unsigned int u = __float_as_uint(f);
    u += 0x7fffu + ((u >> 16) & 1u);
    return (unsigned short)(u >> 16);
}
// sigmoid with pre-scaled input: x = log2e * (raw). sigm = 1/(1+2^-x)
__device__ inline float sigm2(float x){
    float e; asm("v_exp_f32 %0, -%1" : "=v"(e) : "v"(x));
    return __builtin_amdgcn_rcpf(1.0f + e);
}
// tanh(y), y unscaled: t = 2^(-2*log2e*y); tanh = 2/(1+t) - 1
__device__ inline float tanh2(float y){
    float t = y * (-2.0f*LOG2E);
    float e; asm("v_exp_f32 %0, %1" : "=v"(e) : "v"(t));
    return __builtin_fmaf(2.0f, __builtin_amdgcn_rcpf(1.0f + e), -1.0f);
}
__device__ inline float permlane_merge(float d, float s){
    asm("v_permlane32_swap_b32 %0, %1" : "+v"(d), "+v"(s));
    return d;
}
__device__ inline float permlane_merge_v(float d, float s){
    asm volatile("v_permlane32_swap_b32 %0, %1" : "+v"(d), "+v"(s));
    return d;
}
__device__ inline unsigned int cvtpk_bf16(float lo, float hi){
    unsigned int r;
    asm("v_cvt_pk_bf16_f32 %0, %1, %2" : "=v"(r) : "v"(lo), "v"(hi));
    return r;
}
__device__ inline float lo16(unsigned int u){ return __uint_as_float(u << 16); }
__device__ inline float hi16(unsigned int u){ return __uint_as_float(u & 0xffff0000u); }

// prep id-space boundaries
#define TBLE  78336
#define PACKE 471552
#define OUTE  487936
#define PROJE 512512
#define MIDE  578048
#define CNE   579048

__device__ inline float dot64_f4(const float4* a, const float4* b){
    float s = 0.f;
    #pragma unroll
    for (int i=0;i<16;++i){
        float4 x = a[i], y = b[i];
        s = __builtin_fmaf(x.x,y.x,s); s = __builtin_fmaf(x.y,y.y,s);
        s = __builtin_fmaf(x.z,y.z,s); s = __builtin_fmaf(x.w,y.w,s);
    }
    return s;
}

// ---------------- fused prep kernel ----------------
__global__ __launch_bounds__(256) void k_prep(
    const float* __restrict__ enc_emb, const float* __restrict__ enc_wih, const float* __restrict__ enc_bih,
    const float* __restrict__ enc_bhh,
    const float* __restrict__ dec_emb, const float* __restrict__ dec_wih, const float* __restrict__ dec_bih,
    const float* __restrict__ dec_bhh,
    const float* __restrict__ whh_e, const float* __restrict__ whh_d, const float* __restrict__ w_out,
    const float* __restrict__ w_mu, const float* __restrict__ w_std, const float* __restrict__ w_q,
    const float* __restrict__ w_up, const float* __restrict__ cb,
    unsigned short* __restrict__ tep, unsigned short* __restrict__ tdp,
    unsigned short* __restrict__ bpe, unsigned short* __restrict__ bpd,
    unsigned short* __restrict__ bpo,
    float* __restrict__ wTproj, float* __restrict__ wTmid, float* __restrict__ cnorm)
{
    int id = blockIdx.x*256 + threadIdx.x;
    if (id < TBLE){
        int which = id / (V_*768), r = id % (V_*768);
        int v = r / 768, g = r % 768;
        int gate = g >> 8, col = g & 255;
        float s;
        if (!which){
            s = enc_bih[g] + (gate < 2 ? enc_bhh[g] : 0.0f);
            s += dot64_f4((const float4*)(enc_emb + v*64), (const float4*)(enc_wih + g*64));
            if (gate < 2) s *= LOG2E;
            tep[(v*256+col)*4 + gate] = f2bf(s);
        } else {
            s = dec_bih[g] + (gate < 2 ? dec_bhh[g] : 0.0f);
            s += dot64_f4((const float4*)(dec_emb + v*64), (const float4*)(dec_wih + g*128 + 64));
            if (gate < 2) s *= LOG2E;
            tdp[(v*256+col)*4 + gate] = f2bf(s);
        }
    } else if (id < PACKE){
        int rid = id - TBLE;
        int which = rid / 196608, e = rid % 196608;
        int j = e & 7, lane = (e>>3)&63, kt = (e>>9)&7, nt = e>>12;
        int k = kt*32 + (lane>>4)*8 + j, n = nt*16 + (lane&15);
        const float* wmat = which ? whh_d : whh_e;
        float wv = wmat[n*256+k];
        if (nt < 32) wv *= LOG2E;     // r,z gate rows pre-scaled
        (which ? bpd : bpe)[e] = f2bf(wv);
    } else if (id < OUTE){
        int cid = id - PACKE;
        int j = cid & 7, lane = (cid>>3)&63, kt = (cid>>9)&7, nt = cid>>12;
        int k = kt*32 + (lane>>4)*8 + j, n = nt*16 + (lane&15);
        bpo[cid] = f2bf(n < V_ ? w_out[n*256+k] : 0.0f);
    } else if (id < PROJE){
        int e = id - OUTE;                 // wTproj[k*96+o]
        int k = e / 96, o = e % 96;
        float v = (o < 32) ? w_mu[o*H_+k] : (o < 64 ? w_std[(o-32)*H_+k] : w_q[(o-64)*H_+k]);
        wTproj[e] = v;
    } else if (id < MIDE){
        int e = id - PROJE;                // wTmid[k*1024+o]
        int k = e >> 10, o = e & 1023;
        float v;
        if (o < 256) v = w_up[o*64+k];
        else {
            int g = o - 256;
            v = dec_wih[(size_t)g*128 + k];
            if (g < 512) v *= LOG2E;       // r,z gates pre-scaled
        }
        wTmid[e] = v;
    } else if (id < CNE){
        int k = id - MIDE;
        float s = 0.f;
        const float* cv = cb + (size_t)k*Z_;
        for (int ci=0;ci<Z_;++ci) s = __builtin_fmaf(cv[ci],cv[ci],s);
        cnorm[k] = s;
    }
}

// ---------------- GRU recurrence: 256 blocks x 8 batch rows, 8 waves ----------------
// __launch_bounds__(512, 2): 2 waves/EU -> weights stay resident (r3/r5 proven; FETCH ~5.3MB canary).
// Phase-split step: [32 r/z MFMA][r/z gate VALU][16 n MFMA][tail] for cross-wave MFMA/VALU alternation.
template<int DEC>
__global__ __launch_bounds__(512, 2) void k_gru(
    const int* __restrict__ x, const unsigned short* __restrict__ tblg,
    const unsigned short* __restrict__ bpack, const float* __restrict__ bhh,
    const float* __restrict__ h0, const unsigned short* __restrict__ zvp,
    float* __restrict__ h_last, unsigned short* __restrict__ outs)
{
    const int Tn = DEC ? (T_-1) : T_;
    __shared__ alignas(16) unsigned short tbl[V_*1024];   // [v][col][4] bf16
    __shared__ alignas(16) unsigned short hbuf[2*4096];   // [buf][16 rows][256] bf16, swizzled
    __shared__ unsigned int tpk[T_][2];

    const int tid = threadIdx.x;
    const int w = tid>>6, lane = tid&63, lr = lane&15, lp = lane>>4;
    const int b0 = blockIdx.x*8;
    const int jm = w + ((lane>=32)?8:0);
    const int col_m = jm*16 + lr;
    const int rbase = (lp&1)*4;
    const int colm4 = col_m*4;

    // ---- weight fragments resident ----
    const bf16x8* bp = (const bf16x8*)bpack;
    bf16x8 wf[2][3][8];
    #pragma unroll
    for (int ji=0; ji<2; ++ji)
      #pragma unroll
      for (int g=0; g<3; ++g)
        #pragma unroll
        for (int kt=0; kt<8; ++kt)
            wf[ji][g][kt] = bp[(((g*16) + w + 8*ji)*8 + kt)*64 + lane];

    // ---- stage table into LDS ----
    {
        uint4* d4 = (uint4*)tbl; const uint4* s4 = (const uint4*)tblg;
        for (int i=tid; i<(V_*1024)/8; i+=512) d4[i] = s4[i];
    }
    for (int i=tid; i<4096; i+=512){
        int bufi = i>>11, rr = 8 + ((i>>8)&7), c = i&255;
        hbuf[bufi*4096 + rr*256 + c] = 0;
    }
    if (tid < 128){
        int t = tid>>1, g = tid&1;
        unsigned int p = 0;
        #pragma unroll
        for (int r=0;r<4;++r) p |= ((unsigned int)x[(size_t)(b0 + g*4 + r)*T_ + t]) << (8*r);
        tpk[t][g] = p;
    }

    // ---- per-lane state ----
    const float bhn = bhh[2*H_ + col_m];
    float hreg[4];
    int waddr[4];
    #pragma unroll
    for (int q=0; q<4; ++q){
        int row = rbase + q;
        float hv = DEC ? h0[(size_t)(b0+row)*H_ + col_m] : 0.0f;
        hreg[q] = hv;
        waddr[q] = row*256 + (col_m ^ (row<<3));
        hbuf[waddr[q]] = f2bf(hv);
    }
    // DEC: z-projection contribution is t-invariant -> hoist to registers (r,z pre-scaled)
    float zr_[4], zz_[4], zn_[4];
    if (DEC){
        #pragma unroll
        for (int q=0; q<4; ++q){
            const unsigned short* zp = zvp + (((size_t)(b0+rbase+q))*256 + col_m)*4;
            uint2 zv = *(const uint2*)zp;
            zr_[q] = lo16(zv.x); zz_[q] = hi16(zv.x); zn_[q] = lo16(zv.y);
        }
    }
    const int s3 = (lr&7)<<3, lpb = lp*8;
    const int aidx0 = lr*256 + (lpb ^ s3);
    const int aidx1 = lr*256 + ((32 + lpb) ^ s3);
    const int crow = w, cc4 = lane<<2;
    const int csrc = crow*256 + (cc4 ^ (crow<<3));
    unsigned short* cdst0 = DEC ? (outs + ((size_t)(b0+crow)*(T_-1))*H_ + cc4) : nullptr;
    __syncthreads();

#define LDH(i) (*(const bf16x8*)&hbuf[(cur<<12) + (i)])
#define MFMA_(ji,g,kt,av) acc[ji][g] = __builtin_amdgcn_mfma_f32_16x16x32_bf16(av, wf[ji][g][kt], acc[ji][g], 0,0,0)

    auto step = [&](int t, int cur) {
        const int nxt = cur^1;
        unsigned int tp = tpk[t][lp&1];
        floatx4 acc[2][3] = {};

        // ---- all 8 A-fragments once (8 ds_read_b128), live across all chains ----
        bf16x8 a[8];
        #pragma unroll
        for (int kt=0; kt<8; ++kt)
            a[kt] = LDH(((kt&1)?aidx1:aidx0) + ((kt>>1)<<6));

        // gate-input LDS reads (issued early; needed after phase 1)
        uint2 tv[4];
        #pragma unroll
        for (int q=0;q<4;++q){
            int tok = (tp >> (8*q)) & 255;
            tv[q] = *(const uint2*)&tbl[(tok<<10) + colm4];
        }

        // ---- phase 1: r,z chains (32 MFMA) ----
        __builtin_amdgcn_s_setprio(1);
        #pragma unroll
        for (int kt=0; kt<8; ++kt){
            MFMA_(0,0,kt,a[kt]); MFMA_(1,0,kt,a[kt]);
            MFMA_(0,1,kt,a[kt]); MFMA_(1,1,kt,a[kt]);
        }
        __builtin_amdgcn_s_setprio(0);

        // ---- r,z gate VALU (pinned before phase 2 so the other wave's MFMAs overlap) ----
        float rg[4], zg[4];
        #pragma unroll
        for (int q=0;q<4;++q){
            float rm = permlane_merge_v(acc[0][0][q], acc[1][0][q]);
            float xr = lo16(tv[q].x); if (DEC) xr += zr_[q];
            rg[q] = sigm2(xr + rm);
            float zm = permlane_merge_v(acc[0][1][q], acc[1][1][q]);
            float xz = hi16(tv[q].x); if (DEC) xz += zz_[q];
            zg[q] = sigm2(xz + zm);
        }
        __builtin_amdgcn_sched_barrier(0);

        // ---- phase 2: n chains (16 MFMA) ----
        __builtin_amdgcn_s_setprio(1);
        #pragma unroll
        for (int kt=0; kt<8; ++kt){ MFMA_(0,2,kt,a[kt]); MFMA_(1,2,kt,a[kt]); }
        __builtin_amdgcn_s_setprio(0);

        // ---- tail: n gate + h update ----
        float hv[4];
        #pragma unroll
        for (int q=0;q<4;++q){
            float nm = permlane_merge(acc[0][2][q], acc[1][2][q]);
            float xn = lo16(tv[q].y); if (DEC) xn += zn_[q];
            float ng = tanh2(__builtin_fmaf(rg[q], nm + bhn, xn));
            hv[q] = __builtin_fmaf(zg[q], hreg[q] - ng, ng);
            hreg[q] = hv[q];
        }
        unsigned int p01 = cvtpk_bf16(hv[0], hv[1]);
        unsigned int p23 = cvtpk_bf16(hv[2], hv[3]);
        hbuf[(nxt<<12) + waddr[0]] = (unsigned short)p01;
        hbuf[(nxt<<12) + waddr[1]] = (unsigned short)(p01 >> 16);
        hbuf[(nxt<<12) + waddr[2]] = (unsigned short)p23;
        hbuf[(nxt<<12) + waddr[3]] = (unsigned short)(p23 >> 16);
        __syncthreads();
        if (DEC){
            uint2 v = *(const uint2*)&hbuf[(nxt<<12) + csrc];
            *(uint2*)(cdst0 + (size_t)t*H_) = v;
        }
    };

    for (int t=0; t+1<Tn; t+=2){ step(t,0); step(t+1,1); }
    if (Tn & 1) step(Tn-1, 0);

#undef LDH
#undef MFMA_

    if (!DEC){
        #pragma unroll
        for (int q=0; q<4; ++q)
            h_last[(size_t)(b0+rbase+q)*H_ + col_m] = hreg[q];
    }
}

// ---------------- latent+mid: ONE batch row per block, 2048 blocks, coalesced k-major weights ----------------
__global__ __launch_bounds__(256) void k_latmid(
    const float* __restrict__ hlast,
    const float* __restrict__ b_mu, const float* __restrict__ b_std, const float* __restrict__ b_q,
    const float* __restrict__ cb, const float* __restrict__ cnorm,
    const float* __restrict__ wTproj, const float* __restrict__ wTmid,
    const float* __restrict__ b_up,
    float* __restrict__ hidden, unsigned short* __restrict__ zvp,
    float* __restrict__ pKL, float* __restrict__ pQ, float* __restrict__ out_idx)
{
    __shared__ float hs[H_];
    __shared__ float pp[2][96];
    __shared__ float pout[96];     // mu(0..31), lv(32..63), tq(64..95)
    __shared__ float zsl[64];
    __shared__ float rbuf[8];
    __shared__ int   ribuf[8];
    __shared__ int   kbc;
    const int tid = threadIdx.x;
    const int b = blockIdx.x;

    hs[tid] = hlast[(size_t)b*H_ + tid];
    __syncthreads();

    // projections: 2-way k-split, lanes span outputs (coalesced wT reads)
    if (tid < 192){
        int o = tid % 96, kh = tid / 96;
        const float* wp = wTproj + kh*128*96 + o;
        const float* hp = hs + kh*128;
        float s = 0.f;
        #pragma unroll 8
        for (int k=0;k<128;++k) s = __builtin_fmaf(hp[k], wp[k*96], s);
        pp[kh][o] = s;
    }
    __syncthreads();
    if (tid < 96){
        float bias = (tid<32) ? b_mu[tid] : (tid<64 ? b_std[tid-32] : b_q[tid-64]);
        pout[tid] = pp[0][tid] + pp[1][tid] + bias;
    }
    __syncthreads();

    // KL partial (threads 0..31)
    if (tid < 32){
        float m = pout[tid], l = pout[32+tid];
        float kl = 0.5f*(m*m + __expf(l) - l - 1.0f);
        #pragma unroll
        for (int off=16; off>0; off>>=1) kl += __shfl_down(kl, off, 32);
        if (tid==0) pKL[b] = kl;
    }

    // VQ: 4 codes/thread, d = cnorm[k] - 2*dot (row-constant dropped; same decomposition as ref)
    const float* tq = pout + 64;
    float bd = 3.4e38f; int bk = K_;
    #pragma unroll
    for (int c4 = 0; c4 < 4; ++c4){
        int k = tid + c4*256;
        if (k < K_){
            const float4* cr = (const float4*)(cb + (size_t)k*Z_);
            float dot = 0.f;
            #pragma unroll
            for (int j=0;j<8;++j){
                float4 cv = cr[j];
                dot = __builtin_fmaf(cv.x, tq[j*4+0], dot);
                dot = __builtin_fmaf(cv.y, tq[j*4+1], dot);
                dot = __builtin_fmaf(cv.z, tq[j*4+2], dot);
                dot = __builtin_fmaf(cv.w, tq[j*4+3], dot);
            }
            float d = cnorm[k] - 2.0f*dot;
            if (d < bd){ bd = d; bk = k; }     // ascending k -> strict < keeps first index
        }
    }
    #pragma unroll
    for (int off=32; off>0; off>>=1){
        float od = __shfl_down(bd, off, 64);
        int   ok = __shfl_down(bk, off, 64);
        if (od < bd || (od == bd && ok < bk)){ bd = od; bk = ok; }
    }
    if ((tid&63)==0){ rbuf[tid>>6] = bd; ribuf[tid>>6] = bk; }
    __syncthreads();
    if (tid==0){
        float fb = rbuf[0]; int fk = ribuf[0];
        for (int wv=1; wv<4; ++wv)
            if (rbuf[wv] < fb || (rbuf[wv]==fb && ribuf[wv]<fk)){ fb=rbuf[wv]; fk=ribuf[wv]; }
        kbc = fk;
        out_idx[b] = (float)fk;
        float s = 0.f;
        const float* cv = cb + (size_t)fk*Z_;
        for (int ci=0;ci<Z_;++ci){ float df = cv[ci]-tq[ci]; s = __builtin_fmaf(df,df,s); }
        pQ[b] = s*(0.3f/32.0f);
    }
    __syncthreads();
    const int ksel = kbc;
    if (tid < 64) zsl[tid] = (tid < Z_) ? cb[(size_t)ksel*Z_ + tid] : pout[tid-Z_];
    __syncthreads();

    // mid: thread owns outputs o = tid+{0,256,512,768}; all wT loads coalesced
    float a0=0.f, a1=0.f, a2=0.f, a3=0.f;
    const float* wm = wTmid + tid;
    #pragma unroll 8
    for (int k=0;k<64;++k){
        float zk = zsl[k];
        const float* wr = wm + k*1024;
        a0 = __builtin_fmaf(zk, wr[0],   a0);
        a1 = __builtin_fmaf(zk, wr[256], a1);
        a2 = __builtin_fmaf(zk, wr[512], a2);
        a3 = __builtin_fmaf(zk, wr[768], a3);
    }
    hidden[(size_t)b*H_ + tid] = a0 + b_up[tid];
    unsigned int lo = ((unsigned int)f2bf(a2) << 16) | (unsigned int)f2bf(a1);  // r | z<<16
    unsigned int hi = (unsigned int)f2bf(a3);                                   // n
    *(uint2*)(zvp + ((size_t)b*256 + tid)*4) = make_uint2(lo, hi);
}

// ---------------- logits + log_softmax + loss ----------------
__global__ __launch_bounds__(256) void k_loss(
    const unsigned short* __restrict__ outs, const unsigned short* __restrict__ bpo,
    const float* __restrict__ b_out, const int* __restrict__ x,
    float* __restrict__ pred, float* __restrict__ pXL, float* __restrict__ pNP)
{
    __shared__ float ll[16][64];
    __shared__ float bo[64];
    __shared__ float redf[256], redn[256];
    const int tid = threadIdx.x, w = tid>>6, lane = tid&63, lr = lane&15, lp = lane>>4;
    const bf16x8* bpofr = (const bf16x8*)bpo;
    bf16x8 bw[8];
    #pragma unroll
    for (int kt=0;kt<8;++kt) bw[kt] = bpofr[(w*8+kt)*64 + lane];
    if (tid < 64) bo[tid] = (tid < V_) ? b_out[tid] : 0.0f;
    float xl = 0.f, npn = 0.f;
    const int row = tid>>4, vl = tid&15;
    for (int cc=0; cc<4; ++cc){
        int row0 = (blockIdx.x*4 + cc)*16;
        floatx4 acc = {0,0,0,0};
        #pragma unroll
        for (int kt=0;kt<8;++kt){
            bf16x8 av = *(const bf16x8*)&outs[(size_t)(row0+lr)*H_ + kt*32 + lp*8];
            acc = __builtin_amdgcn_mfma_f32_16x16x32_bf16(av, bw[kt], acc, 0,0,0);
        }
        __syncthreads();
        #pragma unroll
        for (int q=0;q<4;++q) ll[lp*4+q][w*16+lr] = acc[q];
        __syncthreads();
        float lv[4];
        #pragma unroll
        for (int k2=0;k2<4;++k2){
            int v = vl + 16*k2;
            lv[k2] = (v < V_) ? ll[row][v] + bo[v] : -3.4e38f;
        }
        float m = lv[0]; int am = vl;
        #pragma unroll
        for (int k2=1;k2<4;++k2){ if (lv[k2] > m){ m = lv[k2]; am = vl + 16*k2; } }
        #pragma unroll
        for (int off=1; off<16; off<<=1){
            float om = __shfl_xor(m, off, 16);
            int oa = __shfl_xor(am, off, 16);
            if (om > m || (om == m && oa < am)){ m = om; am = oa; }
        }
        float se = 0.f;
        #pragma unroll
        for (int k2=0;k2<4;++k2) se += __expf(lv[k2]-m);
        #pragma unroll
        for (int off=1; off<16; off<<=1) se += __shfl_xor(se, off, 16);
        if (vl == 0){
            int rowg = row0 + row;
            int b = rowg/63, tt = rowg - b*63;
            int tgt = x[(size_t)b*T_ + tt + 1];
            pred[rowg] = (float)am;
            if (tgt != 0){
                float lse = m + __logf(se);
                xl += ll[row][tgt] + bo[tgt] - lse;
                npn += 1.f;
            }
        }
    }
    redf[tid]=xl; redn[tid]=npn;
    __syncthreads();
    for (int s=128;s>0;s>>=1){ if (tid<s){ redf[tid]+=redf[tid+s]; redn[tid]+=redn[tid+s]; } __syncthreads(); }
    if (tid==0){ pXL[blockIdx.x]=redf[0]; pNP[blockIdx.x]=redn[0]; }
}

// ---------------- final reduce ----------------
__global__ __launch_bounds__(256) void k_reduce(
    const float* __restrict__ pKL, const float* __restrict__ pQ,
    const float* __restrict__ pXL, const float* __restrict__ pNP, float* __restrict__ dout)
{
    __shared__ float r[256];
    const int tid = threadIdx.x;
    float a = 0.f;
    for (int i=tid;i<2048;i+=256) a += pKL[i];
    r[tid] = a; __syncthreads();
    for (int s=128;s>0;s>>=1){ if (tid<s) r[tid]+=r[tid+s]; __syncthreads(); }
    if (tid==0) dout[129026] = r[0];
    __syncthreads();
    a = 0.f;
    for (int i=tid;i<2048;i+=256) a += pQ[i];
    r[tid] = a; __syncthreads();
    for (int s=128;s>0;s>>=1){ if (tid<s) r[tid]+=r[tid+s]; __syncthreads(); }
    if (tid==0) dout[129027] = r[0];
    __syncthreads();
    a = 0.f;
    for (int i=tid;i<2016;i+=256) a += pXL[i];
    r[tid] = a; __syncthreads();
    for (int s=128;s>0;s>>=1){ if (tid<s) r[tid]+=r[tid+s]; __syncthreads(); }
    if (tid==0) dout[0] = -r[0];
    __syncthreads();
    a = 0.f;
    for (int i=tid;i<2016;i+=256) a += pNP[i];
    r[tid] = a; __syncthreads();
    for (int s=128;s>0;s>>=1){ if (tid<s) r[tid]+=r[tid+s]; __syncthreads(); }
    if (tid==0) dout[1] = r[0];
}

extern "C" void kernel_launch(void* const* d_in, const int* in_sizes, int n_in,
                              void* d_out, int out_size, void* d_ws, size_t ws_size,
                              hipStream_t stream)
{
    const int*   x       = (const int*)  d_in[0];
    const float* enc_emb = (const float*)d_in[1];
    const float* enc_wih = (const float*)d_in[2];
    const float* enc_whh = (const float*)d_in[3];
    const float* enc_bih = (const float*)d_in[4];
    const float* enc_bhh = (const float*)d_in[5];
    const float* w_mu    = (const float*)d_in[6];
    const float* b_mu    = (const float*)d_in[7];
    const float* w_std   = (const float*)d_in[8];
    const float* b_std   = (const float*)d_in[9];
    const float* w_q     = (const float*)d_in[10];
    const float* b_q     = (const float*)d_in[11];
    const float* w_up    = (const float*)d_in[12];
    const float* b_up    = (const float*)d_in[13];
    const float* cb      = (const float*)d_in[14];
    const float* dec_emb = (const float*)d_in[15];
    const float* dec_wih = (const float*)d_in[16];
    const float* dec_whh = (const float*)d_in[17];
    const float* dec_bih = (const float*)d_in[18];
    const float* dec_bhh = (const float*)d_in[19];
    const float* w_out   = (const float*)d_in[20];
    const float* b_out   = (const float*)d_in[21];

    float* ws = (float*)d_ws;
    unsigned short* tep = (unsigned short*)(ws + 0);        // 52224 ush
    unsigned short* tdp = (unsigned short*)(ws + 26112);    // 52224 ush
    unsigned short* bpe = (unsigned short*)(ws + 52224);    // 196608 ush
    unsigned short* bpd = (unsigned short*)(ws + 150528);   // 196608 ush
    unsigned short* bpo = (unsigned short*)(ws + 248832);   // 16384 ush
    float* hl   = ws + 257024;    // 524288
    float* wTproj = ws + 781312;  // 24576  (hole reuse)
    float* wTmid  = ws + 805888;  // 65536
    float* cnorm  = ws + 871424;  // 1000
    float* hid  = ws + 912384;    // 524288
    unsigned short* zvp  = (unsigned short*)(ws + 1436672); // 2097152 ush
    unsigned short* outs = (unsigned short*)(ws + 2485248); // 33030144 ush
    float* pKL  = ws + 19000320;  // 2048
    float* pQ   = ws + 19002368;  // 2048
    float* pXL  = ws + 19004416;  // 2016
    float* pNP  = ws + 19006432;  // 2016

    float* dout = (float*)d_out;

    k_prep<<<2262,256,0,stream>>>(enc_emb, enc_wih, enc_bih, enc_bhh,
                                  dec_emb, dec_wih, dec_bih, dec_bhh,
                                  enc_whh, dec_whh, w_out,
                                  w_mu, w_std, w_q, w_up, cb,
                                  tep, tdp, bpe, bpd, bpo,
                                  wTproj, wTmid, cnorm);
    k_gru<0><<<256,512,0,stream>>>(x, tep, bpe, enc_bhh, nullptr, nullptr, hl, nullptr);
    k_latmid<<<2048,256,0,stream>>>(hl, b_mu, b_std, b_q, cb, cnorm, wTproj, wTmid, b_up,
                                    hid, zvp, pKL, pQ, dout + 129028);
    k_gru<1><<<256,512,0,stream>>>(x, tdp, bpd, dec_bhh, hid, zvp, nullptr, outs);
    k_loss<<<2016,256,0,stream>>>(outs, bpo, b_out, x, dout + 2, pXL, pNP);
    k_reduce<<<1,256,0,stream>>>(pKL, pQ, pXL, pNP, dout);
}

// Round 10
// 284.291 us; speedup vs baseline: 1.5235x; 1.5235x over previous
//
#include <hip/hip_runtime.h>
#include <hip/hip_bf16.h>

#define B_ 2048
#define T_ 64
#define H_ 256
#define V_ 51
#define Z_ 32
#define K_ 1000
#define LOG2E 1.4426950408889634f

typedef __bf16 bf16x8 __attribute__((ext_vector_type(8)));
typedef float floatx4 __attribute__((ext_vector_type(4)));

__device__ inline unsigned short f2bf(float f){
    unsigned int u = __float_as_uint(f);
    u += 0x7fffu + ((u >> 16) & 1u);
    return (unsigned short)(u >> 16);
}
// sigmoid with pre-scaled input: x = log2e * (raw). sigm = 1/(1+2^-x)
__device__ inline float sigm2(float x){
    float e; asm("v_exp_f32 %0, -%1" : "=v"(e) : "v"(x));
    return __builtin_amdgcn_rcpf(1.0f + e);
}
// tanh(y), y unscaled: t = 2^(-2*log2e*y); tanh = 2/(1+t) - 1
__device__ inline float tanh2(float y){
    float t = y * (-2.0f*LOG2E);
    float e; asm("v_exp_f32 %0, %1" : "=v"(e) : "v"(t));
    return __builtin_fmaf(2.0f, __builtin_amdgcn_rcpf(1.0f + e), -1.0f);
}
__device__ inline float permlane_merge(float d, float s){
    asm("v_permlane32_swap_b32 %0, %1" : "+v"(d), "+v"(s));
    return d;
}
__device__ inline unsigned int cvtpk_bf16(float lo, float hi){
    unsigned int r;
    asm("v_cvt_pk_bf16_f32 %0, %1, %2" : "=v"(r) : "v"(lo), "v"(hi));
    return r;
}
__device__ inline float lo16(unsigned int u){ return __uint_as_float(u << 16); }
__device__ inline float hi16(unsigned int u){ return __uint_as_float(u & 0xffff0000u); }

// prep id-space boundaries
#define TBLE  78336
#define PACKE 471552
#define OUTE  487936
#define PROJE 512512
#define MIDE  578048
#define CNE   579048

__device__ inline float dot64_f4(const float4* a, const float4* b){
    float s = 0.f;
    #pragma unroll
    for (int i=0;i<16;++i){
        float4 x = a[i], y = b[i];
        s = __builtin_fmaf(x.x,y.x,s); s = __builtin_fmaf(x.y,y.y,s);
        s = __builtin_fmaf(x.z,y.z,s); s = __builtin_fmaf(x.w,y.w,s);
    }
    return s;
}

// ---------------- fused prep kernel ----------------
__global__ __launch_bounds__(256) void k_prep(
    const float* __restrict__ enc_emb, const float* __restrict__ enc_wih, const float* __restrict__ enc_bih,
    const float* __restrict__ enc_bhh,
    const float* __restrict__ dec_emb, const float* __restrict__ dec_wih, const float* __restrict__ dec_bih,
    const float* __restrict__ dec_bhh,
    const float* __restrict__ whh_e, const float* __restrict__ whh_d, const float* __restrict__ w_out,
    const float* __restrict__ w_mu, const float* __restrict__ w_std, const float* __restrict__ w_q,
    const float* __restrict__ w_up, const float* __restrict__ cb,
    unsigned short* __restrict__ tep, unsigned short* __restrict__ tdp,
    unsigned short* __restrict__ bpe, unsigned short* __restrict__ bpd,
    unsigned short* __restrict__ bpo,
    float* __restrict__ wTproj, float* __restrict__ wTmid, float* __restrict__ cnorm)
{
    int id = blockIdx.x*256 + threadIdx.x;
    if (id < TBLE){
        int which = id / (V_*768), r = id % (V_*768);
        int v = r / 768, g = r % 768;
        int gate = g >> 8, col = g & 255;
        float s;
        if (!which){
            s = enc_bih[g] + (gate < 2 ? enc_bhh[g] : 0.0f);
            s += dot64_f4((const float4*)(enc_emb + v*64), (const float4*)(enc_wih + g*64));
            if (gate < 2) s *= LOG2E;
            tep[(v*256+col)*4 + gate] = f2bf(s);
        } else {
            s = dec_bih[g] + (gate < 2 ? dec_bhh[g] : 0.0f);
            s += dot64_f4((const float4*)(dec_emb + v*64), (const float4*)(dec_wih + g*128 + 64));
            if (gate < 2) s *= LOG2E;
            tdp[(v*256+col)*4 + gate] = f2bf(s);
        }
    } else if (id < PACKE){
        int rid = id - TBLE;
        int which = rid / 196608, e = rid % 196608;
        int j = e & 7, lane = (e>>3)&63, kt = (e>>9)&7, nt = e>>12;
        int k = kt*32 + (lane>>4)*8 + j, n = nt*16 + (lane&15);
        const float* wmat = which ? whh_d : whh_e;
        float wv = wmat[n*256+k];
        if (nt < 32) wv *= LOG2E;     // r,z gate rows pre-scaled
        (which ? bpd : bpe)[e] = f2bf(wv);
    } else if (id < OUTE){
        int cid = id - PACKE;
        int j = cid & 7, lane = (cid>>3)&63, kt = (cid>>9)&7, nt = cid>>12;
        int k = kt*32 + (lane>>4)*8 + j, n = nt*16 + (lane&15);
        bpo[cid] = f2bf(n < V_ ? w_out[n*256+k] : 0.0f);
    } else if (id < PROJE){
        int e = id - OUTE;                 // wTproj[k*96+o]
        int k = e / 96, o = e % 96;
        float v = (o < 32) ? w_mu[o*H_+k] : (o < 64 ? w_std[(o-32)*H_+k] : w_q[(o-64)*H_+k]);
        wTproj[e] = v;
    } else if (id < MIDE){
        int e = id - PROJE;                // wTmid[k*1024+o]
        int k = e >> 10, o = e & 1023;
        float v;
        if (o < 256) v = w_up[o*64+k];
        else {
            int g = o - 256;
            v = dec_wih[(size_t)g*128 + k];
            if (g < 512) v *= LOG2E;       // r,z gates pre-scaled
        }
        wTmid[e] = v;
    } else if (id < CNE){
        int k = id - MIDE;
        float s = 0.f;
        const float* cv = cb + (size_t)k*Z_;
        for (int ci=0;ci<Z_;++ci) s = __builtin_fmaf(cv[ci],cv[ci],s);
        cnorm[k] = s;
    }
}

// ---------------- GRU recurrence: 256 blocks x 8 batch rows, 8 waves ----------------
// __launch_bounds__(512, 2): 2 waves/EU -> weights stay resident.
// r8-proven schedule: monolithic MFMA block, compiler-free scheduling. Do NOT pin
// (r4/r9: any sched_barrier/volatile pinning -> remat+spill, FETCH 5MB->100MB, 2x slower).
template<int DEC>
__global__ __launch_bounds__(512, 2) void k_gru(
    const int* __restrict__ x, const unsigned short* __restrict__ tblg,
    const unsigned short* __restrict__ bpack, const float* __restrict__ bhh,
    const float* __restrict__ h0, const unsigned short* __restrict__ zvp,
    float* __restrict__ h_last, unsigned short* __restrict__ outs)
{
    const int Tn = DEC ? (T_-1) : T_;
    __shared__ alignas(16) unsigned short tbl[V_*1024];   // [v][col][4] bf16
    __shared__ alignas(16) unsigned short hbuf[2*4096];   // [buf][16 rows][256] bf16, swizzled
    __shared__ unsigned int tpk[T_][2];

    const int tid = threadIdx.x;
    const int w = tid>>6, lane = tid&63, lr = lane&15, lp = lane>>4;
    const int b0 = blockIdx.x*8;
    const int jm = w + ((lane>=32)?8:0);
    const int col_m = jm*16 + lr;
    const int rbase = (lp&1)*4;
    const int colm4 = col_m*4;

    // ---- weight fragments resident ----
    const bf16x8* bp = (const bf16x8*)bpack;
    bf16x8 wf[2][3][8];
    #pragma unroll
    for (int ji=0; ji<2; ++ji)
      #pragma unroll
      for (int g=0; g<3; ++g)
        #pragma unroll
        for (int kt=0; kt<8; ++kt)
            wf[ji][g][kt] = bp[(((g*16) + w + 8*ji)*8 + kt)*64 + lane];

    // ---- stage table into LDS ----
    {
        uint4* d4 = (uint4*)tbl; const uint4* s4 = (const uint4*)tblg;
        for (int i=tid; i<(V_*1024)/8; i+=512) d4[i] = s4[i];
    }
    for (int i=tid; i<4096; i+=512){
        int bufi = i>>11, rr = 8 + ((i>>8)&7), c = i&255;
        hbuf[bufi*4096 + rr*256 + c] = 0;
    }
    if (tid < 128){
        int t = tid>>1, g = tid&1;
        unsigned int p = 0;
        #pragma unroll
        for (int r=0;r<4;++r) p |= ((unsigned int)x[(size_t)(b0 + g*4 + r)*T_ + t]) << (8*r);
        tpk[t][g] = p;
    }

    // ---- per-lane state ----
    const float bhn = bhh[2*H_ + col_m];
    float hreg[4];
    int waddr[4];
    #pragma unroll
    for (int q=0; q<4; ++q){
        int row = rbase + q;
        float hv = DEC ? h0[(size_t)(b0+row)*H_ + col_m] : 0.0f;
        hreg[q] = hv;
        waddr[q] = row*256 + (col_m ^ (row<<3));
        hbuf[waddr[q]] = f2bf(hv);
    }
    // DEC: z-projection contribution is t-invariant -> hoist to registers (r,z pre-scaled)
    float zr_[4], zz_[4], zn_[4];
    if (DEC){
        #pragma unroll
        for (int q=0; q<4; ++q){
            const unsigned short* zp = zvp + (((size_t)(b0+rbase+q))*256 + col_m)*4;
            uint2 zv = *(const uint2*)zp;
            zr_[q] = lo16(zv.x); zz_[q] = hi16(zv.x); zn_[q] = lo16(zv.y);
        }
    }
    const int s3 = (lr&7)<<3, lpb = lp*8;
    const int aidx0 = lr*256 + (lpb ^ s3);
    const int aidx1 = lr*256 + ((32 + lpb) ^ s3);
    const int crow = w, cc4 = lane<<2;
    const int csrc = crow*256 + (cc4 ^ (crow<<3));
    unsigned short* cdst0 = DEC ? (outs + ((size_t)(b0+crow)*(T_-1))*H_ + cc4) : nullptr;
    __syncthreads();

#define LDH(i) (*(const bf16x8*)&hbuf[(cur<<12) + (i)])
#define MFMA_(ji,g,kt,av) acc[ji][g] = __builtin_amdgcn_mfma_f32_16x16x32_bf16(av, wf[ji][g][kt], acc[ji][g], 0,0,0)

    auto step = [&](int t, int cur) {
        const int nxt = cur^1;
        unsigned int tp = tpk[t][lp&1];
        floatx4 acc[2][3] = {};

        // ---- all 8 A-fragments once (8 ds_read_b128), live across all chains ----
        bf16x8 a[8];
        #pragma unroll
        for (int kt=0; kt<8; ++kt)
            a[kt] = LDH(((kt&1)?aidx1:aidx0) + ((kt>>1)<<6));

        // gate-input LDS reads (issued early; needed only after MFMAs)
        uint2 tv[4];
        #pragma unroll
        for (int q=0;q<4;++q){
            int tok = (tp >> (8*q)) & 255;
            tv[q] = *(const uint2*)&tbl[(tok<<10) + colm4];
        }

        // ---- 48 MFMAs, kt-major ----
        #pragma unroll
        for (int kt=0; kt<8; ++kt){
            MFMA_(0,0,kt,a[kt]); MFMA_(1,0,kt,a[kt]);
            MFMA_(0,1,kt,a[kt]); MFMA_(1,1,kt,a[kt]);
            MFMA_(0,2,kt,a[kt]); MFMA_(1,2,kt,a[kt]);
        }

        // ---- gate VALU ----
        float rg[4], zg[4], hv[4];
        #pragma unroll
        for (int q=0;q<4;++q){
            float rm = permlane_merge(acc[0][0][q], acc[1][0][q]);
            float xr = lo16(tv[q].x); if (DEC) xr += zr_[q];
            rg[q] = sigm2(xr + rm);
        }
        #pragma unroll
        for (int q=0;q<4;++q){
            float zm = permlane_merge(acc[0][1][q], acc[1][1][q]);
            float xz = hi16(tv[q].x); if (DEC) xz += zz_[q];
            zg[q] = sigm2(xz + zm);
        }
        #pragma unroll
        for (int q=0;q<4;++q){
            float nm = permlane_merge(acc[0][2][q], acc[1][2][q]);
            float xn = lo16(tv[q].y); if (DEC) xn += zn_[q];
            float ng = tanh2(__builtin_fmaf(rg[q], nm + bhn, xn));
            hv[q] = __builtin_fmaf(zg[q], hreg[q] - ng, ng);
            hreg[q] = hv[q];
        }
        unsigned int p01 = cvtpk_bf16(hv[0], hv[1]);
        unsigned int p23 = cvtpk_bf16(hv[2], hv[3]);
        hbuf[(nxt<<12) + waddr[0]] = (unsigned short)p01;
        hbuf[(nxt<<12) + waddr[1]] = (unsigned short)(p01 >> 16);
        hbuf[(nxt<<12) + waddr[2]] = (unsigned short)p23;
        hbuf[(nxt<<12) + waddr[3]] = (unsigned short)(p23 >> 16);
        __syncthreads();
        if (DEC){
            uint2 v = *(const uint2*)&hbuf[(nxt<<12) + csrc];
            *(uint2*)(cdst0 + (size_t)t*H_) = v;
        }
    };

    for (int t=0; t+1<Tn; t+=2){ step(t,0); step(t+1,1); }
    if (Tn & 1) step(Tn-1, 0);

#undef LDH
#undef MFMA_

    if (!DEC){
        #pragma unroll
        for (int q=0; q<4; ++q)
            h_last[(size_t)(b0+rbase+q)*H_ + col_m] = hreg[q];
    }
}

// ---------------- latent+mid: ONE batch row per block, 2048 blocks, coalesced k-major weights ----------------
__global__ __launch_bounds__(256) void k_latmid(
    const float* __restrict__ hlast,
    const float* __restrict__ b_mu, const float* __restrict__ b_std, const float* __restrict__ b_q,
    const float* __restrict__ cb, const float* __restrict__ cnorm,
    const float* __restrict__ wTproj, const float* __restrict__ wTmid,
    const float* __restrict__ b_up,
    float* __restrict__ hidden, unsigned short* __restrict__ zvp,
    float* __restrict__ pKL, float* __restrict__ pQ, float* __restrict__ out_idx)
{
    __shared__ float hs[H_];
    __shared__ float pp[2][96];
    __shared__ float pout[96];     // mu(0..31), lv(32..63), tq(64..95)
    __shared__ float zsl[64];
    __shared__ float rbuf[8];
    __shared__ int   ribuf[8];
    __shared__ int   kbc;
    const int tid = threadIdx.x;
    const int b = blockIdx.x;

    hs[tid] = hlast[(size_t)b*H_ + tid];
    __syncthreads();

    // projections: 2-way k-split, lanes span outputs (coalesced wT reads)
    if (tid < 192){
        int o = tid % 96, kh = tid / 96;
        const float* wp = wTproj + kh*128*96 + o;
        const float* hp = hs + kh*128;
        float s = 0.f;
        #pragma unroll 8
        for (int k=0;k<128;++k) s = __builtin_fmaf(hp[k], wp[k*96], s);
        pp[kh][o] = s;
    }
    __syncthreads();
    if (tid < 96){
        float bias = (tid<32) ? b_mu[tid] : (tid<64 ? b_std[tid-32] : b_q[tid-64]);
        pout[tid] = pp[0][tid] + pp[1][tid] + bias;
    }
    __syncthreads();

    // KL partial (threads 0..31)
    if (tid < 32){
        float m = pout[tid], l = pout[32+tid];
        float kl = 0.5f*(m*m + __expf(l) - l - 1.0f);
        #pragma unroll
        for (int off=16; off>0; off>>=1) kl += __shfl_down(kl, off, 32);
        if (tid==0) pKL[b] = kl;
    }

    // VQ: 4 codes/thread, d = cnorm[k] - 2*dot (row-constant dropped; same decomposition as ref)
    const float* tq = pout + 64;
    float bd = 3.4e38f; int bk = K_;
    #pragma unroll
    for (int c4 = 0; c4 < 4; ++c4){
        int k = tid + c4*256;
        if (k < K_){
            const float4* cr = (const float4*)(cb + (size_t)k*Z_);
            float dot = 0.f;
            #pragma unroll
            for (int j=0;j<8;++j){
                float4 cv = cr[j];
                dot = __builtin_fmaf(cv.x, tq[j*4+0], dot);
                dot = __builtin_fmaf(cv.y, tq[j*4+1], dot);
                dot = __builtin_fmaf(cv.z, tq[j*4+2], dot);
                dot = __builtin_fmaf(cv.w, tq[j*4+3], dot);
            }
            float d = cnorm[k] - 2.0f*dot;
            if (d < bd){ bd = d; bk = k; }     // ascending k -> strict < keeps first index
        }
    }
    #pragma unroll
    for (int off=32; off>0; off>>=1){
        float od = __shfl_down(bd, off, 64);
        int   ok = __shfl_down(bk, off, 64);
        if (od < bd || (od == bd && ok < bk)){ bd = od; bk = ok; }
    }
    if ((tid&63)==0){ rbuf[tid>>6] = bd; ribuf[tid>>6] = bk; }
    __syncthreads();
    if (tid==0){
        float fb = rbuf[0]; int fk = ribuf[0];
        for (int wv=1; wv<4; ++wv)
            if (rbuf[wv] < fb || (rbuf[wv]==fb && ribuf[wv]<fk)){ fb=rbuf[wv]; fk=ribuf[wv]; }
        kbc = fk;
        out_idx[b] = (float)fk;
        float s = 0.f;
        const float* cv = cb + (size_t)fk*Z_;
        for (int ci=0;ci<Z_;++ci){ float df = cv[ci]-tq[ci]; s = __builtin_fmaf(df,df,s); }
        pQ[b] = s*(0.3f/32.0f);
    }
    __syncthreads();
    const int ksel = kbc;
    if (tid < 64) zsl[tid] = (tid < Z_) ? cb[(size_t)ksel*Z_ + tid] : pout[tid-Z_];
    __syncthreads();

    // mid: thread owns outputs o = tid+{0,256,512,768}; all wT loads coalesced
    float a0=0.f, a1=0.f, a2=0.f, a3=0.f;
    const float* wm = wTmid + tid;
    #pragma unroll 8
    for (int k=0;k<64;++k){
        float zk = zsl[k];
        const float* wr = wm + k*1024;
        a0 = __builtin_fmaf(zk, wr[0],   a0);
        a1 = __builtin_fmaf(zk, wr[256], a1);
        a2 = __builtin_fmaf(zk, wr[512], a2);
        a3 = __builtin_fmaf(zk, wr[768], a3);
    }
    hidden[(size_t)b*H_ + tid] = a0 + b_up[tid];
    unsigned int lo = ((unsigned int)f2bf(a2) << 16) | (unsigned int)f2bf(a1);  // r | z<<16
    unsigned int hi = (unsigned int)f2bf(a3);                                   // n
    *(uint2*)(zvp + ((size_t)b*256 + tid)*4) = make_uint2(lo, hi);
}

// ---------------- logits + log_softmax + loss ----------------
__global__ __launch_bounds__(256) void k_loss(
    const unsigned short* __restrict__ outs, const unsigned short* __restrict__ bpo,
    const float* __restrict__ b_out, const int* __restrict__ x,
    float* __restrict__ pred, float* __restrict__ pXL, float* __restrict__ pNP)
{
    __shared__ float ll[16][64];
    __shared__ float bo[64];
    __shared__ float redf[256], redn[256];
    const int tid = threadIdx.x, w = tid>>6, lane = tid&63, lr = lane&15, lp = lane>>4;
    const bf16x8* bpofr = (const bf16x8*)bpo;
    bf16x8 bw[8];
    #pragma unroll
    for (int kt=0;kt<8;++kt) bw[kt] = bpofr[(w*8+kt)*64 + lane];
    if (tid < 64) bo[tid] = (tid < V_) ? b_out[tid] : 0.0f;
    float xl = 0.f, npn = 0.f;
    const int row = tid>>4, vl = tid&15;
    for (int cc=0; cc<4; ++cc){
        int row0 = (blockIdx.x*4 + cc)*16;
        floatx4 acc = {0,0,0,0};
        #pragma unroll
        for (int kt=0;kt<8;++kt){
            bf16x8 av = *(const bf16x8*)&outs[(size_t)(row0+lr)*H_ + kt*32 + lp*8];
            acc = __builtin_amdgcn_mfma_f32_16x16x32_bf16(av, bw[kt], acc, 0,0,0);
        }
        __syncthreads();
        #pragma unroll
        for (int q=0;q<4;++q) ll[lp*4+q][w*16+lr] = acc[q];
        __syncthreads();
        float lv[4];
        #pragma unroll
        for (int k2=0;k2<4;++k2){
            int v = vl + 16*k2;
            lv[k2] = (v < V_) ? ll[row][v] + bo[v] : -3.4e38f;
        }
        float m = lv[0]; int am = vl;
        #pragma unroll
        for (int k2=1;k2<4;++k2){ if (lv[k2] > m){ m = lv[k2]; am = vl + 16*k2; } }
        #pragma unroll
        for (int off=1; off<16; off<<=1){
            float om = __shfl_xor(m, off, 16);
            int oa = __shfl_xor(am, off, 16);
            if (om > m || (om == m && oa < am)){ m = om; am = oa; }
        }
        float se = 0.f;
        #pragma unroll
        for (int k2=0;k2<4;++k2) se += __expf(lv[k2]-m);
        #pragma unroll
        for (int off=1; off<16; off<<=1) se += __shfl_xor(se, off, 16);
        if (vl == 0){
            int rowg = row0 + row;
            int b = rowg/63, tt = rowg - b*63;
            int tgt = x[(size_t)b*T_ + tt + 1];
            pred[rowg] = (float)am;
            if (tgt != 0){
                float lse = m + __logf(se);
                xl += ll[row][tgt] + bo[tgt] - lse;
                npn += 1.f;
            }
        }
    }
    redf[tid]=xl; redn[tid]=npn;
    __syncthreads();
    for (int s=128;s>0;s>>=1){ if (tid<s){ redf[tid]+=redf[tid+s]; redn[tid]+=redn[tid+s]; } __syncthreads(); }
    if (tid==0){ pXL[blockIdx.x]=redf[0]; pNP[blockIdx.x]=redn[0]; }
}

// ---------------- final reduce ----------------
__global__ __launch_bounds__(256) void k_reduce(
    const float* __restrict__ pKL, const float* __restrict__ pQ,
    const float* __restrict__ pXL, const float* __restrict__ pNP, float* __restrict__ dout)
{
    __shared__ float r[256];
    const int tid = threadIdx.x;
    float a = 0.f;
    for (int i=tid;i<2048;i+=256) a += pKL[i];
    r[tid] = a; __syncthreads();
    for (int s=128;s>0;s>>=1){ if (tid<s) r[tid]+=r[tid+s]; __syncthreads(); }
    if (tid==0) dout[129026] = r[0];
    __syncthreads();
    a = 0.f;
    for (int i=tid;i<2048;i+=256) a += pQ[i];
    r[tid] = a; __syncthreads();
    for (int s=128;s>0;s>>=1){ if (tid<s) r[tid]+=r[tid+s]; __syncthreads(); }
    if (tid==0) dout[129027] = r[0];
    __syncthreads();
    a = 0.f;
    for (int i=tid;i<2016;i+=256) a += pXL[i];
    r[tid] = a; __syncthreads();
    for (int s=128;s>0;s>>=1){ if (tid<s) r[tid]+=r[tid+s]; __syncthreads(); }
    if (tid==0) dout[0] = -r[0];
    __syncthreads();
    a = 0.f;
    for (int i=tid;i<2016;i+=256) a += pNP[i];
    r[tid] = a; __syncthreads();
    for (int s=128;s>0;s>>=1){ if (tid<s) r[tid]+=r[tid+s]; __syncthreads(); }
    if (tid==0) dout[1] = r[0];
}

extern "C" void kernel_launch(void* const* d_in, const int* in_sizes, int n_in,
                              void* d_out, int out_size, void* d_ws, size_t ws_size,
                              hipStream_t stream)
{
    const int*   x       = (const int*)  d_in[0];
    const float* enc_emb = (const float*)d_in[1];
    const float* enc_wih = (const float*)d_in[2];
    const float* enc_whh = (const float*)d_in[3];
    const float* enc_bih = (const float*)d_in[4];
    const float* enc_bhh = (const float*)d_in[5];
    const float* w_mu    = (const float*)d_in[6];
    const float* b_mu    = (const float*)d_in[7];
    const float* w_std   = (const float*)d_in[8];
    const float* b_std   = (const float*)d_in[9];
    const float* w_q     = (const float*)d_in[10];
    const float* b_q     = (const float*)d_in[11];
    const float* w_up    = (const float*)d_in[12];
    const float* b_up    = (const float*)d_in[13];
    const float* cb      = (const float*)d_in[14];
    const float* dec_emb = (const float*)d_in[15];
    const float* dec_wih = (const float*)d_in[16];
    const float* dec_whh = (const float*)d_in[17];
    const float* dec_bih = (const float*)d_in[18];
    const float* dec_bhh = (const float*)d_in[19];
    const float* w_out   = (const float*)d_in[20];
    const float* b_out   = (const float*)d_in[21];

    float* ws = (float*)d_ws;
    unsigned short* tep = (unsigned short*)(ws + 0);        // 52224 ush
    unsigned short* tdp = (unsigned short*)(ws + 26112);    // 52224 ush
    unsigned short* bpe = (unsigned short*)(ws + 52224);    // 196608 ush
    unsigned short* bpd = (unsigned short*)(ws + 150528);   // 196608 ush
    unsigned short* bpo = (unsigned short*)(ws + 248832);   // 16384 ush
    float* hl   = ws + 257024;    // 524288
    float* wTproj = ws + 781312;  // 24576  (hole reuse)
    float* wTmid  = ws + 805888;  // 65536
    float* cnorm  = ws + 871424;  // 1000
    float* hid  = ws + 912384;    // 524288
    unsigned short* zvp  = (unsigned short*)(ws + 1436672); // 2097152 ush
    unsigned short* outs = (unsigned short*)(ws + 2485248); // 33030144 ush
    float* pKL  = ws + 19000320;  // 2048
    float* pQ   = ws + 19002368;  // 2048
    float* pXL  = ws + 19004416;  // 2016
    float* pNP  = ws + 19006432;  // 2016

    float* dout = (float*)d_out;

    k_prep<<<2262,256,0,stream>>>(enc_emb, enc_wih, enc_bih, enc_bhh,
                                  dec_emb, dec_wih, dec_bih, dec_bhh,
                                  enc_whh, dec_whh, w_out,
                                  w_mu, w_std, w_q, w_up, cb,
                                  tep, tdp, bpe, bpd, bpo,
                                  wTproj, wTmid, cnorm);
    k_gru<0><<<256,512,0,stream>>>(x, tep, bpe, enc_bhh, nullptr, nullptr, hl, nullptr);
    k_latmid<<<2048,256,0,stream>>>(hl, b_mu, b_std, b_q, cb, cnorm, wTproj, wTmid, b_up,
                                    hid, zvp, pKL, pQ, dout + 129028);
    k_gru<1><<<256,512,0,stream>>>(x, tdp, bpd, dec_bhh, hid, zvp, nullptr, outs);
    k_loss<<<2016,256,0,stream>>>(outs, bpo, b_out, x, dout + 2, pXL, pNP);
    k_reduce<<<1,256,0,stream>>>(pKL, pQ, pXL, pNP, dout);
}

// Round 11
// 258.200 us; speedup vs baseline: 1.6774x; 1.1010x over previous
//
#include <hip/hip_runtime.h>
#include <hip/hip_bf16.h>

#define B_ 2048
#define T_ 64
#define H_ 256
#define V_ 51
#define Z_ 32
#define K_ 1000
#define LOG2E 1.4426950408889634f

typedef __bf16 bf16x8 __attribute__((ext_vector_type(8)));
typedef float floatx4 __attribute__((ext_vector_type(4)));

__device__ inline unsigned short f2bf(float f){
    unsigned int u = __float_as_uint(f);
    u += 0x7fffu + ((u >> 16) & 1u);
    return (unsigned short)(u >> 16);
}
// sigmoid with pre-scaled input: x = log2e * (raw). sigm = 1/(1+2^-x)
__device__ inline float sigm2(float x){
    float e; asm("v_exp_f32 %0, -%1" : "=v"(e) : "v"(x));
    return __builtin_amdgcn_rcpf(1.0f + e);
}
// tanh(y), y unscaled: t = 2^(-2*log2e*y); tanh = 2/(1+t) - 1
__device__ inline float tanh2(float y){
    float t = y * (-2.0f*LOG2E);
    float e; asm("v_exp_f32 %0, %1" : "=v"(e) : "v"(t));
    return __builtin_fmaf(2.0f, __builtin_amdgcn_rcpf(1.0f + e), -1.0f);
}
__device__ inline float permlane_merge(float d, float s){
    asm("v_permlane32_swap_b32 %0, %1" : "+v"(d), "+v"(s));
    return d;
}
__device__ inline unsigned int cvtpk_bf16(float lo, float hi){
    unsigned int r;
    asm("v_cvt_pk_bf16_f32 %0, %1, %2" : "=v"(r) : "v"(lo), "v"(hi));
    return r;
}
__device__ inline float lo16(unsigned int u){ return __uint_as_float(u << 16); }
__device__ inline float hi16(unsigned int u){ return __uint_as_float(u & 0xffff0000u); }

// prep id-space boundaries
#define TBLE  78336
#define PACKE 471552
#define OUTE  487936
#define PROJE 512512
#define MIDE  578048
#define CNE   579048

__device__ inline float dot64_f4(const float4* a, const float4* b){
    float s = 0.f;
    #pragma unroll
    for (int i=0;i<16;++i){
        float4 x = a[i], y = b[i];
        s = __builtin_fmaf(x.x,y.x,s); s = __builtin_fmaf(x.y,y.y,s);
        s = __builtin_fmaf(x.z,y.z,s); s = __builtin_fmaf(x.w,y.w,s);
    }
    return s;
}

// ---------------- fused prep kernel ----------------
__global__ __launch_bounds__(256) void k_prep(
    const float* __restrict__ enc_emb, const float* __restrict__ enc_wih, const float* __restrict__ enc_bih,
    const float* __restrict__ enc_bhh,
    const float* __restrict__ dec_emb, const float* __restrict__ dec_wih, const float* __restrict__ dec_bih,
    const float* __restrict__ dec_bhh,
    const float* __restrict__ whh_e, const float* __restrict__ whh_d, const float* __restrict__ w_out,
    const float* __restrict__ w_mu, const float* __restrict__ w_std, const float* __restrict__ w_q,
    const float* __restrict__ w_up, const float* __restrict__ cb,
    unsigned short* __restrict__ tep, unsigned short* __restrict__ tdp,
    unsigned short* __restrict__ bpe, unsigned short* __restrict__ bpd,
    unsigned short* __restrict__ bpo,
    float* __restrict__ wTproj, float* __restrict__ wTmid, float* __restrict__ cnorm)
{
    int id = blockIdx.x*256 + threadIdx.x;
    if (id < TBLE){
        int which = id / (V_*768), r = id % (V_*768);
        int v = r / 768, g = r % 768;
        int gate = g >> 8, col = g & 255;
        float s;
        if (!which){
            s = enc_bih[g] + (gate < 2 ? enc_bhh[g] : 0.0f);
            s += dot64_f4((const float4*)(enc_emb + v*64), (const float4*)(enc_wih + g*64));
            if (gate < 2) s *= LOG2E;
            tep[(v*256+col)*4 + gate] = f2bf(s);
        } else {
            s = dec_bih[g] + (gate < 2 ? dec_bhh[g] : 0.0f);
            s += dot64_f4((const float4*)(dec_emb + v*64), (const float4*)(dec_wih + g*128 + 64));
            if (gate < 2) s *= LOG2E;
            tdp[(v*256+col)*4 + gate] = f2bf(s);
        }
    } else if (id < PACKE){
        int rid = id - TBLE;
        int which = rid / 196608, e = rid % 196608;
        int j = e & 7, lane = (e>>3)&63, kt = (e>>9)&7, nt = e>>12;
        int k = kt*32 + (lane>>4)*8 + j, n = nt*16 + (lane&15);
        const float* wmat = which ? whh_d : whh_e;
        float wv = wmat[n*256+k];
        if (nt < 32) wv *= LOG2E;     // r,z gate rows pre-scaled
        (which ? bpd : bpe)[e] = f2bf(wv);
    } else if (id < OUTE){
        int cid = id - PACKE;
        int j = cid & 7, lane = (cid>>3)&63, kt = (cid>>9)&7, nt = cid>>12;
        int k = kt*32 + (lane>>4)*8 + j, n = nt*16 + (lane&15);
        bpo[cid] = f2bf(n < V_ ? w_out[n*256+k] : 0.0f);
    } else if (id < PROJE){
        int e = id - OUTE;                 // wTproj[k*96+o]
        int k = e / 96, o = e % 96;
        float v = (o < 32) ? w_mu[o*H_+k] : (o < 64 ? w_std[(o-32)*H_+k] : w_q[(o-64)*H_+k]);
        wTproj[e] = v;
    } else if (id < MIDE){
        int e = id - PROJE;                // wTmid[k*1024+o]
        int k = e >> 10, o = e & 1023;
        float v;
        if (o < 256) v = w_up[o*64+k];
        else {
            int g = o - 256;
            v = dec_wih[(size_t)g*128 + k];
            if (g < 512) v *= LOG2E;       // r,z gates pre-scaled
        }
        wTmid[e] = v;
    } else if (id < CNE){
        int k = id - MIDE;
        float s = 0.f;
        const float* cv = cb + (size_t)k*Z_;
        for (int ci=0;ci<Z_;++ci) s = __builtin_fmaf(cv[ci],cv[ci],s);
        cnorm[k] = s;
    }
}

// ---------------- GRU recurrence: 256 blocks x 8 batch rows, 8 waves ----------------
// __launch_bounds__(512, 2): 2 waves/EU -> weights stay resident.
// r8-proven schedule: monolithic MFMA block, compiler-free scheduling. Do NOT pin
// (r4/r9: any sched_barrier/volatile pinning -> remat+spill, FETCH 5MB->100MB, 2x slower).
template<int DEC>
__global__ __launch_bounds__(512, 2) void k_gru(
    const int* __restrict__ x, const unsigned short* __restrict__ tblg,
    const unsigned short* __restrict__ bpack, const float* __restrict__ bhh,
    const float* __restrict__ h0, const unsigned short* __restrict__ zvp,
    float* __restrict__ h_last, unsigned short* __restrict__ outs)
{
    const int Tn = DEC ? (T_-1) : T_;
    __shared__ alignas(16) unsigned short tbl[V_*1024];   // [v][col][4] bf16
    __shared__ alignas(16) unsigned short hbuf[2*4096];   // [buf][16 rows][256] bf16, swizzled
    __shared__ unsigned int tpk[T_][2];

    const int tid = threadIdx.x;
    const int w = tid>>6, lane = tid&63, lr = lane&15, lp = lane>>4;
    const int b0 = blockIdx.x*8;
    const int jm = w + ((lane>=32)?8:0);
    const int col_m = jm*16 + lr;
    const int rbase = (lp&1)*4;
    const int colm4 = col_m*4;

    // ---- weight fragments resident ----
    const bf16x8* bp = (const bf16x8*)bpack;
    bf16x8 wf[2][3][8];
    #pragma unroll
    for (int ji=0; ji<2; ++ji)
      #pragma unroll
      for (int g=0; g<3; ++g)
        #pragma unroll
        for (int kt=0; kt<8; ++kt)
            wf[ji][g][kt] = bp[(((g*16) + w + 8*ji)*8 + kt)*64 + lane];

    // ---- stage table into LDS ----
    {
        uint4* d4 = (uint4*)tbl; const uint4* s4 = (const uint4*)tblg;
        for (int i=tid; i<(V_*1024)/8; i+=512) d4[i] = s4[i];
    }
    for (int i=tid; i<4096; i+=512){
        int bufi = i>>11, rr = 8 + ((i>>8)&7), c = i&255;
        hbuf[bufi*4096 + rr*256 + c] = 0;
    }
    if (tid < 128){
        int t = tid>>1, g = tid&1;
        unsigned int p = 0;
        #pragma unroll
        for (int r=0;r<4;++r) p |= ((unsigned int)x[(size_t)(b0 + g*4 + r)*T_ + t]) << (8*r);
        tpk[t][g] = p;
    }

    // ---- per-lane state ----
    const float bhn = bhh[2*H_ + col_m];
    float hreg[4];
    int waddr[4];
    #pragma unroll
    for (int q=0; q<4; ++q){
        int row = rbase + q;
        float hv = DEC ? h0[(size_t)(b0+row)*H_ + col_m] : 0.0f;
        hreg[q] = hv;
        waddr[q] = row*256 + (col_m ^ (row<<3));
        hbuf[waddr[q]] = f2bf(hv);
    }
    // DEC: z-projection contribution is t-invariant -> hoist to registers (r,z pre-scaled)
    float zr_[4], zz_[4], zn_[4];
    if (DEC){
        #pragma unroll
        for (int q=0; q<4; ++q){
            const unsigned short* zp = zvp + (((size_t)(b0+rbase+q))*256 + col_m)*4;
            uint2 zv = *(const uint2*)zp;
            zr_[q] = lo16(zv.x); zz_[q] = hi16(zv.x); zn_[q] = lo16(zv.y);
        }
    }
    const int s3 = (lr&7)<<3, lpb = lp*8;
    const int aidx0 = lr*256 + (lpb ^ s3);
    const int aidx1 = lr*256 + ((32 + lpb) ^ s3);
    const int crow = w, cc4 = lane<<2;
    const int csrc = crow*256 + (cc4 ^ (crow<<3));
    unsigned short* cdst0 = DEC ? (outs + ((size_t)(b0+crow)*(T_-1))*H_ + cc4) : nullptr;
    __syncthreads();

#define LDH(i) (*(const bf16x8*)&hbuf[(cur<<12) + (i)])
#define MFMA_(ji,g,kt,av) acc[ji][g] = __builtin_amdgcn_mfma_f32_16x16x32_bf16(av, wf[ji][g][kt], acc[ji][g], 0,0,0)

    auto step = [&](int t, int cur) {
        const int nxt = cur^1;
        unsigned int tp = tpk[t][lp&1];
        floatx4 acc[2][3] = {};

        // ---- all 8 A-fragments once (8 ds_read_b128), live across all chains ----
        bf16x8 a[8];
        #pragma unroll
        for (int kt=0; kt<8; ++kt)
            a[kt] = LDH(((kt&1)?aidx1:aidx0) + ((kt>>1)<<6));

        // gate-input LDS reads (issued early; needed only after MFMAs)
        uint2 tv[4];
        #pragma unroll
        for (int q=0;q<4;++q){
            int tok = (tp >> (8*q)) & 255;
            tv[q] = *(const uint2*)&tbl[(tok<<10) + colm4];
        }

        // ---- 48 MFMAs, kt-major ----
        #pragma unroll
        for (int kt=0; kt<8; ++kt){
            MFMA_(0,0,kt,a[kt]); MFMA_(1,0,kt,a[kt]);
            MFMA_(0,1,kt,a[kt]); MFMA_(1,1,kt,a[kt]);
            MFMA_(0,2,kt,a[kt]); MFMA_(1,2,kt,a[kt]);
        }

        // ---- gate VALU ----
        float rg[4], zg[4], hv[4];
        #pragma unroll
        for (int q=0;q<4;++q){
            float rm = permlane_merge(acc[0][0][q], acc[1][0][q]);
            float xr = lo16(tv[q].x); if (DEC) xr += zr_[q];
            rg[q] = sigm2(xr + rm);
        }
        #pragma unroll
        for (int q=0;q<4;++q){
            float zm = permlane_merge(acc[0][1][q], acc[1][1][q]);
            float xz = hi16(tv[q].x); if (DEC) xz += zz_[q];
            zg[q] = sigm2(xz + zm);
        }
        #pragma unroll
        for (int q=0;q<4;++q){
            float nm = permlane_merge(acc[0][2][q], acc[1][2][q]);
            float xn = lo16(tv[q].y); if (DEC) xn += zn_[q];
            float ng = tanh2(__builtin_fmaf(rg[q], nm + bhn, xn));
            hv[q] = __builtin_fmaf(zg[q], hreg[q] - ng, ng);
            hreg[q] = hv[q];
        }
        unsigned int p01 = cvtpk_bf16(hv[0], hv[1]);
        unsigned int p23 = cvtpk_bf16(hv[2], hv[3]);
        hbuf[(nxt<<12) + waddr[0]] = (unsigned short)p01;
        hbuf[(nxt<<12) + waddr[1]] = (unsigned short)(p01 >> 16);
        hbuf[(nxt<<12) + waddr[2]] = (unsigned short)p23;
        hbuf[(nxt<<12) + waddr[3]] = (unsigned short)(p23 >> 16);
        __syncthreads();
        if (DEC){
            uint2 v = *(const uint2*)&hbuf[(nxt<<12) + csrc];
            *(uint2*)(cdst0 + (size_t)t*H_) = v;
        }
    };

    for (int t=0; t+1<Tn; t+=2){ step(t,0); step(t+1,1); }
    if (Tn & 1) step(Tn-1, 0);

#undef LDH
#undef MFMA_

    if (!DEC){
        #pragma unroll
        for (int q=0; q<4; ++q)
            h_last[(size_t)(b0+rbase+q)*H_ + col_m] = hreg[q];
    }
}

// ---------------- latent+mid v3: 256 blocks x 8 rows — weights read ONCE per block ----------------
// v2 at 2048 blocks re-read all weights per block (~970MB L2 traffic, ~28us floor).
// v3 amortizes 8x: wTproj/wTmid/cb element loaded once per block, tq broadcast from LDS.
__global__ __launch_bounds__(256) void k_latmid(
    const float* __restrict__ hlast,
    const float* __restrict__ b_mu, const float* __restrict__ b_std, const float* __restrict__ b_q,
    const float* __restrict__ cb, const float* __restrict__ cnorm,
    const float* __restrict__ wTproj, const float* __restrict__ wTmid,
    const float* __restrict__ b_up,
    float* __restrict__ hidden, unsigned short* __restrict__ zvp,
    float* __restrict__ pKL, float* __restrict__ pQ, float* __restrict__ out_idx)
{
    __shared__ float hs[8][H_];        // 8KB
    __shared__ float pp[2][8][96];     // 6KB
    __shared__ float pout[8][96];      // mu(0..31), lv(32..63), tq(64..95) per row
    __shared__ float zsl[8][64];
    __shared__ float dval[8][256];     // 8KB
    __shared__ int   didx[8][256];     // 8KB
    __shared__ float redk[8], redq[8];
    __shared__ int   ksel[8];
    const int tid = threadIdx.x;
    const int b0 = blockIdx.x*8;

    for (int i=tid; i<8*H_; i+=256) hs[i>>8][i&255] = hlast[(size_t)b0*H_ + i];
    __syncthreads();

    // projections: thread (o, kh) computes partials for ALL 8 rows; wTproj read once/block
    if (tid < 192){
        int o = tid % 96, kh = tid / 96;
        const float* wp = wTproj + kh*128*96 + o;
        float s[8] = {0,0,0,0,0,0,0,0};
        for (int k=0;k<128;++k){
            float wv = wp[k*96];
            #pragma unroll
            for (int r=0;r<8;++r) s[r] = __builtin_fmaf(hs[r][kh*128+k], wv, s[r]);
        }
        #pragma unroll
        for (int r=0;r<8;++r) pp[kh][r][o] = s[r];
    }
    __syncthreads();
    for (int id=tid; id<768; id+=256){
        int o = id % 96, r = id / 96;
        float bias = (o<32) ? b_mu[o] : (o<64 ? b_std[o-32] : b_q[o-64]);
        pout[r][o] = pp[0][r][o] + pp[1][r][o] + bias;
    }
    __syncthreads();

    // KL: thread (r=tid>>5, zi=tid&31)
    {
        int r = tid>>5, zi = tid&31;
        float m = pout[r][zi], l = pout[r][32+zi];
        float kl = 0.5f*(m*m + __expf(l) - l - 1.0f);
        #pragma unroll
        for (int off=16; off>0; off>>=1) kl += __shfl_down(kl, off, 32);
        if (zi==0) redk[r] = kl;
    }

    // VQ: 4 codes/thread x 8 rows; cb row in regs, tq LDS-broadcast (uniform address)
    float best[8]; int bi[8];
    #pragma unroll
    for (int r=0;r<8;++r){ best[r] = 3.4e38f; bi[r] = K_; }
    #pragma unroll
    for (int c4=0; c4<4; ++c4){
        int k = tid + c4*256;
        if (k < K_){
            const float4* cr = (const float4*)(cb + (size_t)k*Z_);
            float4 cv[8];
            #pragma unroll
            for (int j=0;j<8;++j) cv[j] = cr[j];
            float cn = cnorm[k];
            #pragma unroll
            for (int r=0;r<8;++r){
                float dot = 0.f;
                #pragma unroll
                for (int j=0;j<8;++j){
                    dot = __builtin_fmaf(cv[j].x, pout[r][64+j*4+0], dot);
                    dot = __builtin_fmaf(cv[j].y, pout[r][64+j*4+1], dot);
                    dot = __builtin_fmaf(cv[j].z, pout[r][64+j*4+2], dot);
                    dot = __builtin_fmaf(cv[j].w, pout[r][64+j*4+3], dot);
                }
                float d = __builtin_fmaf(-2.0f, dot, cn);
                if (d < best[r]){ best[r] = d; bi[r] = k; }   // ascending k -> first-index ties
            }
        }
    }
    #pragma unroll
    for (int r=0;r<8;++r){ dval[r][tid] = best[r]; didx[r][tid] = bi[r]; }
    __syncthreads();
    {
        int r = tid>>5, c = tid&31;
        float bm = 3.4e38f; int bx = K_+1;
        #pragma unroll
        for (int e=0;e<8;++e){
            int j = c + e*32;
            float dv = dval[r][j]; int di = didx[r][j];
            if (dv < bm || (dv == bm && di < bx)){ bm = dv; bx = di; }
        }
        #pragma unroll
        for (int off=16; off>0; off>>=1){
            float om = __shfl_xor(bm, off, 32);
            int   oi = __shfl_xor(bx, off, 32);
            if (om < bm || (om == bm && oi < bx)){ bm = om; bx = oi; }
        }
        if (c == 0){
            ksel[r] = bx;
            out_idx[b0+r] = (float)bx;
            float s = 0.f;
            const float* cv = cb + (size_t)bx*Z_;
            for (int ci=0;ci<Z_;++ci){ float df = cv[ci]-pout[r][64+ci]; s = __builtin_fmaf(df,df,s); }
            redq[r] = s*(0.3f/32.0f);
        }
    }
    __syncthreads();
    if (tid==0){
        float q=0.f, kl=0.f;
        #pragma unroll
        for (int r=0;r<8;++r){ q += redq[r]; kl += redk[r]; }
        pQ[blockIdx.x] = q; pKL[blockIdx.x] = kl;
    }
    for (int id=tid; id<512; id+=256){
        int r = id>>6, cc = id&63;
        zsl[r][cc] = (cc < Z_) ? cb[(size_t)ksel[r]*Z_ + cc] : pout[r][cc-Z_];
    }
    __syncthreads();

    // mid: thread owns cols o=tid+{0,256,512,768} for ALL 8 rows; wTmid read once/block
    float a0[8]={0,0,0,0,0,0,0,0}, a1[8]={0,0,0,0,0,0,0,0};
    float a2[8]={0,0,0,0,0,0,0,0}, a3[8]={0,0,0,0,0,0,0,0};
    const float* wm = wTmid + tid;
    for (int k=0;k<64;++k){
        const float* wr = wm + k*1024;
        float w0 = wr[0], w1 = wr[256], w2 = wr[512], w3 = wr[768];
        #pragma unroll
        for (int r=0;r<8;++r){
            float zk = zsl[r][k];
            a0[r] = __builtin_fmaf(zk, w0, a0[r]);
            a1[r] = __builtin_fmaf(zk, w1, a1[r]);
            a2[r] = __builtin_fmaf(zk, w2, a2[r]);
            a3[r] = __builtin_fmaf(zk, w3, a3[r]);
        }
    }
    float bup = b_up[tid];
    #pragma unroll
    for (int r=0;r<8;++r){
        hidden[(size_t)(b0+r)*H_ + tid] = a0[r] + bup;
        unsigned int lo = ((unsigned int)f2bf(a2[r]) << 16) | (unsigned int)f2bf(a1[r]);  // r | z<<16
        unsigned int hi = (unsigned int)f2bf(a3[r]);                                      // n
        *(uint2*)(zvp + ((size_t)(b0+r)*256 + tid)*4) = make_uint2(lo, hi);
    }
}

// ---------------- logits + log_softmax + loss ----------------
__global__ __launch_bounds__(256) void k_loss(
    const unsigned short* __restrict__ outs, const unsigned short* __restrict__ bpo,
    const float* __restrict__ b_out, const int* __restrict__ x,
    float* __restrict__ pred, float* __restrict__ pXL, float* __restrict__ pNP)
{
    __shared__ float ll[16][64];
    __shared__ float bo[64];
    __shared__ float redf[256], redn[256];
    const int tid = threadIdx.x, w = tid>>6, lane = tid&63, lr = lane&15, lp = lane>>4;
    const bf16x8* bpofr = (const bf16x8*)bpo;
    bf16x8 bw[8];
    #pragma unroll
    for (int kt=0;kt<8;++kt) bw[kt] = bpofr[(w*8+kt)*64 + lane];
    if (tid < 64) bo[tid] = (tid < V_) ? b_out[tid] : 0.0f;
    float xl = 0.f, npn = 0.f;
    const int row = tid>>4, vl = tid&15;
    for (int cc=0; cc<4; ++cc){
        int row0 = (blockIdx.x*4 + cc)*16;
        floatx4 acc = {0,0,0,0};
        #pragma unroll
        for (int kt=0;kt<8;++kt){
            bf16x8 av = *(const bf16x8*)&outs[(size_t)(row0+lr)*H_ + kt*32 + lp*8];
            acc = __builtin_amdgcn_mfma_f32_16x16x32_bf16(av, bw[kt], acc, 0,0,0);
        }
        __syncthreads();
        #pragma unroll
        for (int q=0;q<4;++q) ll[lp*4+q][w*16+lr] = acc[q];
        __syncthreads();
        float lv[4];
        #pragma unroll
        for (int k2=0;k2<4;++k2){
            int v = vl + 16*k2;
            lv[k2] = (v < V_) ? ll[row][v] + bo[v] : -3.4e38f;
        }
        float m = lv[0]; int am = vl;
        #pragma unroll
        for (int k2=1;k2<4;++k2){ if (lv[k2] > m){ m = lv[k2]; am = vl + 16*k2; } }
        #pragma unroll
        for (int off=1; off<16; off<<=1){
            float om = __shfl_xor(m, off, 16);
            int oa = __shfl_xor(am, off, 16);
            if (om > m || (om == m && oa < am)){ m = om; am = oa; }
        }
        float se = 0.f;
        #pragma unroll
        for (int k2=0;k2<4;++k2) se += __expf(lv[k2]-m);
        #pragma unroll
        for (int off=1; off<16; off<<=1) se += __shfl_xor(se, off, 16);
        if (vl == 0){
            int rowg = row0 + row;
            int b = rowg/63, tt = rowg - b*63;
            int tgt = x[(size_t)b*T_ + tt + 1];
            pred[rowg] = (float)am;
            if (tgt != 0){
                float lse = m + __logf(se);
                xl += ll[row][tgt] + bo[tgt] - lse;
                npn += 1.f;
            }
        }
    }
    redf[tid]=xl; redn[tid]=npn;
    __syncthreads();
    for (int s=128;s>0;s>>=1){ if (tid<s){ redf[tid]+=redf[tid+s]; redn[tid]+=redn[tid+s]; } __syncthreads(); }
    if (tid==0){ pXL[blockIdx.x]=redf[0]; pNP[blockIdx.x]=redn[0]; }
}

// ---------------- final reduce ----------------
__global__ __launch_bounds__(256) void k_reduce(
    const float* __restrict__ pKL, const float* __restrict__ pQ,
    const float* __restrict__ pXL, const float* __restrict__ pNP, float* __restrict__ dout)
{
    __shared__ float r[256];
    const int tid = threadIdx.x;
    r[tid] = pKL[tid]; __syncthreads();
    for (int s=128;s>0;s>>=1){ if (tid<s) r[tid]+=r[tid+s]; __syncthreads(); }
    if (tid==0) dout[129026] = r[0];
    __syncthreads();
    r[tid] = pQ[tid]; __syncthreads();
    for (int s=128;s>0;s>>=1){ if (tid<s) r[tid]+=r[tid+s]; __syncthreads(); }
    if (tid==0) dout[129027] = r[0];
    __syncthreads();
    float a = 0.f;
    for (int i=tid;i<2016;i+=256) a += pXL[i];
    r[tid] = a; __syncthreads();
    for (int s=128;s>0;s>>=1){ if (tid<s) r[tid]+=r[tid+s]; __syncthreads(); }
    if (tid==0) dout[0] = -r[0];
    __syncthreads();
    a = 0.f;
    for (int i=tid;i<2016;i+=256) a += pNP[i];
    r[tid] = a; __syncthreads();
    for (int s=128;s>0;s>>=1){ if (tid<s) r[tid]+=r[tid+s]; __syncthreads(); }
    if (tid==0) dout[1] = r[0];
}

extern "C" void kernel_launch(void* const* d_in, const int* in_sizes, int n_in,
                              void* d_out, int out_size, void* d_ws, size_t ws_size,
                              hipStream_t stream)
{
    const int*   x       = (const int*)  d_in[0];
    const float* enc_emb = (const float*)d_in[1];
    const float* enc_wih = (const float*)d_in[2];
    const float* enc_whh = (const float*)d_in[3];
    const float* enc_bih = (const float*)d_in[4];
    const float* enc_bhh = (const float*)d_in[5];
    const float* w_mu    = (const float*)d_in[6];
    const float* b_mu    = (const float*)d_in[7];
    const float* w_std   = (const float*)d_in[8];
    const float* b_std   = (const float*)d_in[9];
    const float* w_q     = (const float*)d_in[10];
    const float* b_q     = (const float*)d_in[11];
    const float* w_up    = (const float*)d_in[12];
    const float* b_up    = (const float*)d_in[13];
    const float* cb      = (const float*)d_in[14];
    const float* dec_emb = (const float*)d_in[15];
    const float* dec_wih = (const float*)d_in[16];
    const float* dec_whh = (const float*)d_in[17];
    const float* dec_bih = (const float*)d_in[18];
    const float* dec_bhh = (const float*)d_in[19];
    const float* w_out   = (const float*)d_in[20];
    const float* b_out   = (const float*)d_in[21];

    float* ws = (float*)d_ws;
    unsigned short* tep = (unsigned short*)(ws + 0);        // 52224 ush
    unsigned short* tdp = (unsigned short*)(ws + 26112);    // 52224 ush
    unsigned short* bpe = (unsigned short*)(ws + 52224);    // 196608 ush
    unsigned short* bpd = (unsigned short*)(ws + 150528);   // 196608 ush
    unsigned short* bpo = (unsigned short*)(ws + 248832);   // 16384 ush
    float* hl   = ws + 257024;    // 524288
    float* wTproj = ws + 781312;  // 24576  (hole reuse)
    float* wTmid  = ws + 805888;  // 65536
    float* cnorm  = ws + 871424;  // 1000
    float* hid  = ws + 912384;    // 524288
    unsigned short* zvp  = (unsigned short*)(ws + 1436672); // 2097152 ush
    unsigned short* outs = (unsigned short*)(ws + 2485248); // 33030144 ush
    float* pKL  = ws + 19000320;  // 256
    float* pQ   = ws + 19002368;  // 256
    float* pXL  = ws + 19004416;  // 2016
    float* pNP  = ws + 19006432;  // 2016

    float* dout = (float*)d_out;

    k_prep<<<2262,256,0,stream>>>(enc_emb, enc_wih, enc_bih, enc_bhh,
                                  dec_emb, dec_wih, dec_bih, dec_bhh,
                                  enc_whh, dec_whh, w_out,
                                  w_mu, w_std, w_q, w_up, cb,
                                  tep, tdp, bpe, bpd, bpo,
                                  wTproj, wTmid, cnorm);
    k_gru<0><<<256,512,0,stream>>>(x, tep, bpe, enc_bhh, nullptr, nullptr, hl, nullptr);
    k_latmid<<<256,256,0,stream>>>(hl, b_mu, b_std, b_q, cb, cnorm, wTproj, wTmid, b_up,
                                   hid, zvp, pKL, pQ, dout + 129028);
    k_gru<1><<<256,512,0,stream>>>(x, tdp, bpd, dec_bhh, hid, zvp, nullptr, outs);
    k_loss<<<2016,256,0,stream>>>(outs, bpo, b_out, x, dout + 2, pXL, pNP);
    k_reduce<<<1,256,0,stream>>>(pKL, pQ, pXL, pNP, dout);
}